// Round 14
// baseline (137.565 us; speedup 1.0000x reference)
//
#include <hip/hip_runtime.h>
#include <hip/hip_bf16.h>

typedef unsigned short u16;
typedef unsigned int u32;
typedef __attribute__((ext_vector_type(8))) short short8;
typedef __attribute__((ext_vector_type(4))) unsigned short ush4;
typedef __attribute__((ext_vector_type(16))) float f32x16;

// ---------------------------------------------------------------------------
// ws layout (float units): see prior rounds.
// ---------------------------------------------------------------------------
#define OXT   0
#define OSI   (OXT + 8388608)
#define OA    (OSI + 98304)
#define OB    (OA + 2097152)
#define OC    (OB + 2097152)
#define OOFFS (OC + 2097152)
#define OMSK  (OOFFS + 1179648)
#define OWT   (OMSK + 294912)
#define OWSP1 (OWT + 589824)
#define OBSP1 (OWSP1 + 1728)
#define OWSP2 (OBSP1 + 64)
#define OBSP2 (OWSP2 + 36864)
#define OWSP3 (OBSP2 + 64)
#define OBSP3 (OWSP3 + 36864)
#define OWOFF (OBSP3 + 64)
#define OBOFF (OWOFF + 36864)
#define OWDC  (OBOFF + 64)

__device__ __forceinline__ u16 f2bf(float f) {
    __hip_bfloat16 hb = __float2bfloat16(f);
    return __builtin_bit_cast(u16, hb);
}
__device__ __forceinline__ float bf2f(u16 v) {
    return __builtin_bit_cast(float, (u32)v << 16);
}
// XOR slot swizzle: data (kg, px) lives at row kg, slot = px with low3 ^ kg.
__device__ __forceinline__ int sswz(int kg, int px) {
    return (px & ~7) | ((px ^ kg) & 7);
}

// corner table for one (tap, pixel): 4 addresses (element offsets) + weights
__device__ __forceinline__ void corner_tab_big(
    int tap, int pix0, int b, int gp,
    const float* __restrict__ offs, const float* __restrict__ maskb,
    int* car, float* cwr)
{
    int pix = pix0 + gp; int pib = pix & 4095;
    int y = pib >> 6, x = pib & 63;
    float offy = offs[(size_t)pix * 36 + tap * 2];
    float offx = offs[(size_t)pix * 36 + tap * 2 + 1];
    float m = maskb[(size_t)pix * 9 + tap];
    float py = (float)(y - 1 + tap / 3) + offy;
    float pxf = (float)(x - 1 + (tap % 3)) + offx;
    float fy = floorf(py), fx = floorf(pxf);
    int y0 = (int)fy, x0 = (int)fx;
    float dyf = py - fy, dxf = pxf - fx;
    #pragma unroll
    for (int j = 0; j < 4; j++) {
        float wj = ((j >> 1) ? dyf : 1.f - dyf) * ((j & 1) ? dxf : 1.f - dxf);
        int yy = y0 + (j >> 1), xx = x0 + (j & 1);
        bool valid = (yy >= 0 && yy < 64 && xx >= 0 && xx < 64);
        int yc = min(max(yy, 0), 63), xc = min(max(xx, 0), 63);
        car[j] = (b * 4096 + yc * 64 + xc) << 8;
        cwr[j] = valid ? wj * m : 0.f;
    }
}

__device__ __forceinline__ void corner_tab_small(
    int tap, int pix0, int b, int gp,
    const float* __restrict__ offs, int* car, float* cwr)
{
    int pix = pix0 + gp; int pib = pix & 4095;
    int y = pib >> 6, x = pib & 63;
    float offy = offs[(size_t)pix * 36 + 18 + tap * 2];
    float offx = offs[(size_t)pix * 36 + 18 + tap * 2 + 1];
    float py = (float)(y - 1 + tap / 3) + offy;
    float pxf = (float)(x - 1 + (tap % 3)) + offx;
    float fy = floorf(py), fx = floorf(pxf);
    int y0 = (int)fy, x0 = (int)fx;
    float dyf = py - fy, dxf = pxf - fx;
    #pragma unroll
    for (int j = 0; j < 4; j++) {
        float wj = ((j >> 1) ? dyf : 1.f - dyf) * ((j & 1) ? dxf : 1.f - dxf);
        int yy = y0 + (j >> 1), xx = x0 + (j & 1);
        bool valid = (yy >= 0 && yy < 64 && xx >= 0 && xx < 64);
        int yc = min(max(yy, 0), 63), xc = min(max(xx, 0), 63);
        car[j] = (b * 4096 + yc * 64 + xc) << 6;
        cwr[j] = valid ? wj : 0.f;
    }
}

// ---------------------------------------------------------------------------
// Fused prologue: prep (blocks 0..2887) | transpose_x (2888..4935) |
// resize (4936..5319).
// ---------------------------------------------------------------------------
__global__ __launch_bounds__(256) void prologue_k(
    const float* __restrict__ weight,
    const float* __restrict__ sp_w1, const float* __restrict__ sp_s1,
    const float* __restrict__ sp_w2, const float* __restrict__ sp_s2,
    const float* __restrict__ sp_w3, const float* __restrict__ sp_s3,
    const float* __restrict__ off_w, const float* __restrict__ dc_off_w,
    const float* __restrict__ dc_w,
    const float* __restrict__ sp_b1, const float* __restrict__ sp_o1,
    const float* __restrict__ sp_b2, const float* __restrict__ sp_o2,
    const float* __restrict__ sp_b3, const float* __restrict__ sp_o3,
    const float* __restrict__ off_b, const float* __restrict__ dc_off_b,
    const float* __restrict__ x, const float* __restrict__ S,
    float* __restrict__ ws)
{
    __shared__ float tile[64][65];
    int blk = blockIdx.x;
    int t = threadIdx.x;

    if (blk >= 4936) {                       // ---- resize ----
        int i = (blk - 4936) * 256 + t;
        if (i >= 8 * 64 * 64 * 3) return;
        int c = i % 3; int xq = (i / 3) & 63; int y = (i / 192) & 63; int b = i / 12288;
        const float sc = 127.0f / 63.0f;
        float sy = y * sc, sx = xq * sc;
        float fy = floorf(sy), fx = floorf(sx);
        int y0 = (int)fy, x0 = (int)fx;
        int y1 = min(y0 + 1, 127), x1 = min(x0 + 1, 127);
        float wy = sy - fy, wx = sx - fx;
        const float* Sb = S + (size_t)(b * 3 + c) * 16384;
        float v00 = Sb[y0 * 128 + x0], v01 = Sb[y0 * 128 + x1];
        float v10 = Sb[y1 * 128 + x0], v11 = Sb[y1 * 128 + x1];
        (ws + OSI)[i] = (v00 * (1.f - wy) + v10 * wy) * (1.f - wx)
                      + (v01 * (1.f - wy) + v11 * wy) * wx;
        return;
    }
    if (blk >= 2888) {                       // ---- transpose x -> xT bf16 ----
        int bb = blk - 2888;
        int chunk = bb & 3; int by = bb >> 2;
        int b = by >> 6; int y = by & 63;
        int c0 = chunk * 64;
        u16* xT = (u16*)(ws + OXT);
        for (int i = t; i < 4096; i += 256) {
            int ci = i >> 6, xi = i & 63;
            tile[ci][xi] = x[((b * 256 + c0 + ci) * 64 + y) * 64 + xi];
        }
        __syncthreads();
        for (int i = t; i < 4096; i += 256) {
            int xi = i >> 6, ci = i & 63;
            xT[((b * 64 + y) * 64 + xi) * 256 + c0 + ci] = f2bf(tile[ci][xi]);
        }
        return;
    }
    // ---- prep ----
    int i = blk * 256 + t;
    if (i < 589824) {   // wKg bf16 [kg][o][j], K=kg*8+j = k*256+c
        int j = i & 7; int o = (i >> 3) & 255; int kg = i >> 11;
        int K = kg * 8 + j; int k = K >> 8; int c = K & 255;
        ((u16*)(ws + OWT))[i] = f2bf(weight[o * 2304 + c * 9 + k]);
        return;
    }
    i -= 589824;
    if (i < 1728) {     // wsp1 f32 [9][3][64]
        int o = i & 63; int kc = i >> 6; int c = kc % 3; int k = kc / 3;
        ws[OWSP1 + i] = sp_w1[(o * 3 + c) * 9 + k] * sp_s1[o];
        return;
    }
    i -= 1728;
    if (i < 36864) {    // wm2 bf16 [t][kg][o][e]
        int e = i & 7; int o = (i >> 3) & 63; int kg = (i >> 9) & 7; int tp = i >> 12;
        ((u16*)(ws + OWSP2))[i] = f2bf(sp_w2[(o * 64 + kg * 8 + e) * 9 + tp] * sp_s2[o]);
        return;
    }
    i -= 36864;
    if (i < 36864) {
        int e = i & 7; int o = (i >> 3) & 63; int kg = (i >> 9) & 7; int tp = i >> 12;
        ((u16*)(ws + OWSP3))[i] = f2bf(sp_w3[(o * 64 + kg * 8 + e) * 9 + tp] * sp_s3[o]);
        return;
    }
    i -= 36864;
    if (i < 36864) {    // woff bf16
        int e = i & 7; int o = (i >> 3) & 63; int kg = (i >> 9) & 7; int tp = i >> 12;
        int c = kg * 8 + e;
        float v = 0.f;
        if (o < 18) v = off_w[(o * 64 + c) * 9 + tp];
        else if (o < 36) v = dc_off_w[((o - 18) * 64 + c) * 9 + tp];
        ((u16*)(ws + OWOFF))[i] = f2bf(v);
        return;
    }
    i -= 36864;
    if (i < 36864) {    // wdc bf16 [t][kg][o][e]
        int e = i & 7; int o = (i >> 3) & 63; int kg = (i >> 9) & 7; int tp = i >> 12;
        ((u16*)(ws + OWDC))[i] = f2bf(dc_w[(o * 64 + kg * 8 + e) * 9 + tp]);
        return;
    }
    i -= 36864;
    if (i < 64) { ws[OBSP1 + i] = sp_b1[i] * sp_s1[i] + sp_o1[i]; return; }
    i -= 64;
    if (i < 64) { ws[OBSP2 + i] = sp_b2[i] * sp_s2[i] + sp_o2[i]; return; }
    i -= 64;
    if (i < 64) { ws[OBSP3 + i] = sp_b3[i] * sp_s3[i] + sp_o3[i]; return; }
    i -= 64;
    if (i < 64) { ws[OBOFF + i] = (i < 18) ? off_b[i] : (i < 36 ? dc_off_b[i - 18] : 0.f); return; }
}

// conv1: 3->64, fp32 VALU, bf16 NHWC output. One block per (b,y) row.
__global__ __launch_bounds__(256) void conv_in_k(const float* __restrict__ in,
                                                 const float* __restrict__ wt,
                                                 const float* __restrict__ bias,
                                                 u16* __restrict__ out)
{
    __shared__ float rows[3][66][3];
    int by = blockIdx.x; int b = by >> 6; int y = by & 63;
    int t = threadIdx.x;
    for (int i = t; i < 3 * 66 * 3; i += 256) {
        int r = i / 198; int rem = i - r * 198;
        int xi = rem / 3; int c = rem - xi * 3;
        int yy = y - 1 + r, xx = xi - 1;
        float v = 0.f;
        if (yy >= 0 && yy < 64 && xx >= 0 && xx < 64)
            v = in[(((b * 64 + yy) * 64 + xx) * 3) + c];
        rows[r][xi][c] = v;
    }
    __syncthreads();
    int o4 = (t & 15) * 4; int xg = t >> 4;
    float acc[4][4];
    #pragma unroll
    for (int oi = 0; oi < 4; oi++) {
        float bv = bias[o4 + oi];
        #pragma unroll
        for (int xi = 0; xi < 4; xi++) acc[oi][xi] = bv;
    }
    for (int k = 0; k < 9; k++) {
        int dy = k / 3, dx = k - 3 * (k / 3);
        for (int c = 0; c < 3; c++) {
            float4 w = *reinterpret_cast<const float4*>(&wt[(k * 3 + c) * 64 + o4]);
            #pragma unroll
            for (int xi = 0; xi < 4; xi++) {
                float iv = rows[dy][xg * 4 + xi + dx][c];
                acc[0][xi] = fmaf(w.x, iv, acc[0][xi]);
                acc[1][xi] = fmaf(w.y, iv, acc[1][xi]);
                acc[2][xi] = fmaf(w.z, iv, acc[2][xi]);
                acc[3][xi] = fmaf(w.w, iv, acc[3][xi]);
            }
        }
    }
    #pragma unroll
    for (int xi = 0; xi < 4; xi++) {
        int x = xg * 4 + xi;
        ush4 v;
        v.x = f2bf(fmaxf(acc[0][xi], 0.f));
        v.y = f2bf(fmaxf(acc[1][xi], 0.f));
        v.z = f2bf(fmaxf(acc[2][xi], 0.f));
        v.w = f2bf(fmaxf(acc[3][xi], 0.f));
        *reinterpret_cast<ush4*>(&out[((size_t)(by * 64 + x)) * 64 + o4]) = v;
    }
}

// ---------------------------------------------------------------------------
// MFMA 3x3 conv 64->64. Block: 1 output row (64 px), 4 waves = 2(o) x 2(px).
// wtap 3-buffer, prefetch 2 taps ahead, counted vmcnt(2) (not 0).
// ---------------------------------------------------------------------------
template <int MODE, bool RELU>
__global__ __launch_bounds__(256) void conv_mfma_k(const u16* __restrict__ in,
                                                   const u16* __restrict__ wm,
                                                   const float* __restrict__ bias,
                                                   u16* __restrict__ outH,
                                                   float* __restrict__ outF)
{
    __shared__ __attribute__((aligned(16))) char lds_h[3 * 66 * 128];   // 25344 B
    __shared__ __attribute__((aligned(16))) u16 wtap[3][8][64][8];      // 24576 B

    int t = threadIdx.x;
    int b = blockIdx.x >> 6; int y = blockIdx.x & 63;
    int pix0 = b * 4096 + y * 64;
    int wid = t >> 6, lane = t & 63;
    int lrow = lane & 31, lhi = lane >> 5;
    int o0 = (wid & 1) << 5;
    int px0 = (wid >> 1) << 5;
    int px = px0 + lrow;

    for (int i = t; i < 3 * 66 * 8; i += 256) {
        int r = i / 528; int rem = i - r * 528;
        int xi = rem >> 3; int g = rem & 7;
        int yy = y - 1 + r, xx = xi - 1;
        short8 v = {0,0,0,0,0,0,0,0};
        if (yy >= 0 && yy < 64 && xx >= 0 && xx < 64)
            v = *reinterpret_cast<const short8*>(&in[(size_t)((b * 4096 + yy * 64 + xx)) * 64 + g * 8]);
        int byte = (r * 66 + xi) * 128 + ((g * 16) ^ ((xi & 7) << 4));
        *reinterpret_cast<short8*>(lds_h + byte) = v;
    }
    // stage tap0 + tap1 weights
    #pragma unroll
    for (int p = 0; p < 2; p++) {
        const char* gb = (const char*)(wm + (size_t)p * 4096);
        char* lb = (char*)&wtap[p][0][0][0];
        #pragma unroll
        for (int i = 0; i < 2; i++) {
            int off = i * 4096 + wid * 1024;
            __builtin_amdgcn_global_load_lds(
                (const __attribute__((address_space(1))) void*)(gb + off + lane * 16),
                (__attribute__((address_space(3))) void*)(lb + off), 16, 0, 0);
        }
    }
    __syncthreads();

    f32x16 acc;
    #pragma unroll
    for (int r = 0; r < 16; r++) acc[r] = 0.f;

    #pragma unroll
    for (int tap = 0; tap < 9; tap++) {
        int cur = tap % 3;
        if (tap < 7) {
            int nb = (tap + 2) % 3;
            const char* gb = (const char*)(wm + (size_t)(tap + 2) * 4096);
            char* lb = (char*)&wtap[nb][0][0][0];
            #pragma unroll
            for (int i = 0; i < 2; i++) {
                int off = i * 4096 + wid * 1024;
                __builtin_amdgcn_global_load_lds(
                    (const __attribute__((address_space(1))) void*)(gb + off + lane * 16),
                    (__attribute__((address_space(3))) void*)(lb + off), 16, 0, 0);
            }
        }
        int dy = tap / 3, dx = tap - 3 * (tap / 3);
        int xi = px + dx;
        int rowbyte = (dy * 66 + xi) * 128;
        int swz = (xi & 7) << 4;
        #pragma unroll
        for (int ks = 0; ks < 4; ks++) {
            int kg = ks * 2 + lhi;
            short8 a0 = *reinterpret_cast<const short8*>(&wtap[cur][kg][o0 + lrow][0]);
            short8 b0 = *reinterpret_cast<const short8*>(lds_h + rowbyte + ((kg * 16) ^ swz));
            acc = __builtin_amdgcn_mfma_f32_32x32x16_bf16(a0, b0, acc, 0, 0, 0);
        }
        if (tap < 8) {
            if (tap < 7) asm volatile("s_waitcnt vmcnt(2)" ::: "memory");
            else         asm volatile("s_waitcnt vmcnt(0)" ::: "memory");
            __builtin_amdgcn_s_barrier();
        }
    }
    __syncthreads();

    if (MODE == 0) {
        #pragma unroll
        for (int q = 0; q < 4; q++) {
            int ob = o0 + q * 8 + 4 * lhi;
            #pragma unroll
            for (int h = 0; h < 2; h++) {
                float v0 = acc[q * 4 + h * 2] + bias[ob + h * 2];
                float v1 = acc[q * 4 + h * 2 + 1] + bias[ob + h * 2 + 1];
                if (RELU) { v0 = fmaxf(v0, 0.f); v1 = fmaxf(v1, 0.f); }
                u32 pk = (u32)f2bf(v0) | ((u32)f2bf(v1) << 16);
                int byte = px * 128 + (((ob + h * 2) * 2) ^ ((px & 7) << 4));
                *reinterpret_cast<u32*>(lds_h + byte) = pk;
            }
        }
        __syncthreads();
        #pragma unroll
        for (int i = 0; i < 2; i++) {
            int cid = i * 256 + t;
            int p = cid >> 3, g = cid & 7;
            short8 v = *reinterpret_cast<const short8*>(lds_h + p * 128 + ((g * 16) ^ ((p & 7) << 4)));
            *reinterpret_cast<short8*>(&outH[(size_t)(pix0 + p) * 64 + g * 8]) = v;
        }
    } else {
        float* ltf = (float*)lds_h;
        #pragma unroll
        for (int r = 0; r < 16; r++) {
            int o = o0 + (r & 3) + ((r >> 2) << 3) + (lhi << 2);
            if (o < 36) ltf[px * 40 + o] = acc[r] + bias[o];
        }
        __syncthreads();
        for (int i = t; i < 576; i += 256) {
            int p = i / 9, q = i - 9 * (i / 9);
            float4 v = *reinterpret_cast<const float4*>(&ltf[p * 40 + q * 4]);
            *reinterpret_cast<float4*>(&outF[(size_t)(pix0 + p) * 36 + q * 4]) = v;
        }
    }
}

// ---------------------------------------------------------------------------
// DCNv1 on h (bf16, 64->64) + fused mask head.
// Now with reg-gather prefetch + counted vmcnt(8) (round-11 pipeline).
// ---------------------------------------------------------------------------
__global__ __launch_bounds__(512) void dconv_small_mfma(
    const u16* __restrict__ h, const float* __restrict__ offs,
    const u16* __restrict__ wdc, const float* __restrict__ m_w,
    const float* __restrict__ m_b, float* __restrict__ maskb)
{
    __shared__ __attribute__((aligned(16))) char smem[49152];
    u16 (*wtile)[8][64][8]  = (u16 (*)[8][64][8])smem;            // [2][8][64][8]  16KB
    u16 (*stile)[8][128][8] = (u16 (*)[8][128][8])(smem + 16384); // [2][8][128][8] 32KB

    int t = threadIdx.x;
    int id = blockIdx.x;
    int blk = (id & 7) * 32 + (id >> 3);      // XCD swizzle
    int pix0 = blk * 128;
    int b = pix0 >> 12;
    int wid = t >> 6, lane = t & 63;
    int lrow = lane & 31, lhi = lane >> 5;
    int o0 = (wid & 1) << 5;
    int px0 = (wid >> 1) << 5;
    int gp = t >> 2, gsub = t & 3;            // pixel / 16-ch chunk

    int car[4]; float cwr[4];
    short8 g[8];

    // prologue: corners tap0, gather tap0 to regs, weight DMA tap0
    corner_tab_small(0, pix0, b, gp, offs, car, cwr);
    {
        int c = gsub << 4;
        #pragma unroll
        for (int j = 0; j < 4; j++) {
            const u16* p = h + car[j] + c;
            g[j * 2]     = *reinterpret_cast<const short8*>(p);
            g[j * 2 + 1] = *reinterpret_cast<const short8*>(p + 8);
        }
    }
    {
        const char* gb = (const char*)wdc;
        char* lb = (char*)&wtile[0][0][0][0];
        __builtin_amdgcn_global_load_lds(
            (const __attribute__((address_space(1))) void*)(gb + wid * 1024 + lane * 16),
            (__attribute__((address_space(3))) void*)(lb + wid * 1024), 16, 0, 0);
    }

    f32x16 acc;
    #pragma unroll
    for (int r = 0; r < 16; r++) acc[r] = 0.f;

    for (int tap = 0; tap < 9; ++tap) {
        int cur = tap & 1, nxt = cur ^ 1;

        // interp(tap): consume g regs -> stile[cur]
        float va[16];
        #pragma unroll
        for (int e = 0; e < 16; e++) va[e] = 0.f;
        #pragma unroll
        for (int j = 0; j < 4; j++) {
            float w = cwr[j];
            #pragma unroll
            for (int e = 0; e < 8; e++) {
                va[e]     = fmaf(w, bf2f((u16)g[j * 2][e]), va[e]);
                va[8 + e] = fmaf(w, bf2f((u16)g[j * 2 + 1][e]), va[8 + e]);
            }
        }
        short8 s0, s1;
        #pragma unroll
        for (int e = 0; e < 8; e++) { s0[e] = (short)f2bf(va[e]); s1[e] = (short)f2bf(va[8 + e]); }
        int kg0 = gsub * 2, kg1 = gsub * 2 + 1;
        *reinterpret_cast<short8*>(&stile[cur][kg0][sswz(kg0, gp)][0]) = s0;
        *reinterpret_cast<short8*>(&stile[cur][kg1][sswz(kg1, gp)][0]) = s1;

        if (tap < 8) {
            corner_tab_small(tap + 1, pix0, b, gp, offs, car, cwr);
            int c = gsub << 4;
            #pragma unroll
            for (int j = 0; j < 4; j++) {
                const u16* p = h + car[j] + c;
                g[j * 2]     = *reinterpret_cast<const short8*>(p);
                g[j * 2 + 1] = *reinterpret_cast<const short8*>(p + 8);
            }
            // keep 8 fresh gather loads in flight; drain weight DMA (oldest)
            asm volatile("s_waitcnt vmcnt(8) lgkmcnt(0)" ::: "memory");
        } else {
            asm volatile("s_waitcnt vmcnt(0) lgkmcnt(0)" ::: "memory");
        }
        __builtin_amdgcn_s_barrier();

        #pragma unroll
        for (int ks = 0; ks < 4; ks++) {
            int kg = ks * 2 + lhi;
            short8 a0 = *reinterpret_cast<const short8*>(&wtile[cur][kg][o0 + lrow][0]);
            short8 b0 = *reinterpret_cast<const short8*>(&stile[cur][kg][sswz(kg, px0 + lrow)][0]);
            acc = __builtin_amdgcn_mfma_f32_32x32x16_bf16(a0, b0, acc, 0, 0, 0);
        }
        // post-barrier weight DMA for tap+1
        if (tap < 8) {
            const char* gb = (const char*)(wdc + (size_t)(tap + 1) * 4096);
            char* lb = (char*)&wtile[nxt][0][0][0];
            __builtin_amdgcn_global_load_lds(
                (const __attribute__((address_space(1))) void*)(gb + wid * 1024 + lane * 16),
                (__attribute__((address_space(3))) void*)(lb + wid * 1024), 16, 0, 0);
        }
    }

    // epilogue: feat -> LDS [128][65] f32, then fused mask
    __syncthreads();
    float* featl = (float*)smem;
    int pxl = px0 + lrow;
    #pragma unroll
    for (int r = 0; r < 16; r++) {
        int o = o0 + (r & 3) + ((r >> 2) << 3) + (lhi << 2);
        featl[pxl * 65 + o] = acc[r];
    }
    __syncthreads();
    if (t < 256) {
        int p = t >> 1, hh = t & 1;
        int pix = pix0 + p;
        const float* fr = &featl[p * 65];
        int j0 = hh ? 4 : 0, j1 = hh ? 9 : 4;
        for (int j = j0; j < j1; j++) {
            float a = m_b[j];
            #pragma unroll 8
            for (int cc = 0; cc < 64; cc++) a = fmaf(fr[cc], m_w[j * 64 + cc], a);
            maskb[(size_t)pix * 9 + j] = 1.f / (1.f + expf(-a));
        }
    }
}

// ---------------------------------------------------------------------------
// Modulated DCNv2 (256->256), bf16 MFMA, v5.
// 512 blocks x 512 thr; block = 64 px x 256 o; 8 waves = 8(o) x 1(px),
// wave tile 32o x 64px (acc[2]). LDS = wtile dbuf 64KB + stile dbuf 16KB
// = exactly 80KB -> 2 blocks/CU (4 waves/SIMD cross-block TLP).
// Reg-gather prefetch (4 loads) + counted vmcnt(4); single barrier per kt.
// ---------------------------------------------------------------------------
__global__ __launch_bounds__(512) void dconv_big_mfma(
    const u16* __restrict__ xT, const float* __restrict__ offs,
    const float* __restrict__ maskb, const u16* __restrict__ wKg,
    const float* __restrict__ bias, float* __restrict__ out)
{
    __shared__ __attribute__((aligned(16))) u16 wtile[2][8][256][8];  // 64 KB
    __shared__ __attribute__((aligned(16))) u16 stile[2][8][64][8];   // 16 KB

    int t = threadIdx.x;
    int id = blockIdx.x;                       // 512
    int blk = (id & 7) * 64 + (id >> 3);       // XCD swizzle
    int pix0 = blk * 64;
    int b = pix0 >> 12, pib0 = pix0 & 4095;
    int wid = t >> 6, lane = t & 63;
    int lrow = lane & 31, lhi = lane >> 5;
    int o0 = wid << 5;                         // 8 o-groups of 32
    int gp = t >> 3, gsub = t & 7;             // gather pixel / 8-ch chunk

    int car[4]; float cwr[4];
    short8 g[4];

    // prologue: corners tap0, gather kt0 to regs, weight DMA kt0
    corner_tab_big(0, pix0, b, gp, offs, maskb, car, cwr);
    {
        int c = gsub << 3;
        #pragma unroll
        for (int j = 0; j < 4; j++)
            g[j] = *reinterpret_cast<const short8*>(xT + car[j] + c);
    }
    {
        const char* gb = (const char*)wKg;
        char* lb = (char*)&wtile[0][0][0][0];
        #pragma unroll
        for (int i = 0; i < 4; i++) {
            int off = i * 8192 + wid * 1024;
            __builtin_amdgcn_global_load_lds(
                (const __attribute__((address_space(1))) void*)(gb + off + lane * 16),
                (__attribute__((address_space(3))) void*)(lb + off), 16, 0, 0);
        }
    }

    f32x16 acc[2];
    #pragma unroll
    for (int fp = 0; fp < 2; fp++)
        #pragma unroll
        for (int r = 0; r < 16; r++) acc[fp][r] = 0.f;

    for (int kt = 0; kt < 36; ++kt) {
        int cur = kt & 1, nxt = cur ^ 1;

        // interp(kt): consume g regs -> stile[cur]
        float va[8];
        #pragma unroll
        for (int e = 0; e < 8; e++) va[e] = 0.f;
        #pragma unroll
        for (int j = 0; j < 4; j++) {
            float w = cwr[j];
            #pragma unroll
            for (int e = 0; e < 8; e++) va[e] = fmaf(w, bf2f((u16)g[j][e]), va[e]);
        }
        short8 s0;
        #pragma unroll
        for (int e = 0; e < 8; e++) s0[e] = (short)f2bf(va[e]);
        *reinterpret_cast<short8*>(&stile[cur][gsub][sswz(gsub, gp)][0]) = s0;

        // next corners + issue gather(kt+1) into regs
        if (kt < 35) {
            if (((kt + 1) & 3) == 0)
                corner_tab_big((kt + 1) >> 2, pix0, b, gp, offs, maskb, car, cwr);
            int c = (((kt + 1) & 3) << 6) + (gsub << 3);
            #pragma unroll
            for (int j = 0; j < 4; j++)
                g[j] = *reinterpret_cast<const short8*>(xT + car[j] + c);
            // outstanding: weight DMA(4, oldest) + gather(4 fresh) -> drain DMA
            asm volatile("s_waitcnt vmcnt(4) lgkmcnt(0)" ::: "memory");
        } else {
            asm volatile("s_waitcnt vmcnt(0) lgkmcnt(0)" ::: "memory");
        }
        __builtin_amdgcn_s_barrier();

        // MFMA(kt): wave = 32o x 64px
        #pragma unroll
        for (int ks = 0; ks < 4; ks++) {
            int kg = ks * 2 + lhi;
            short8 a0 = *reinterpret_cast<const short8*>(&wtile[cur][kg][o0 + lrow][0]);
            short8 b0 = *reinterpret_cast<const short8*>(&stile[cur][kg][sswz(kg, lrow)][0]);
            short8 b1 = *reinterpret_cast<const short8*>(&stile[cur][kg][sswz(kg, 32 + lrow)][0]);
            acc[0] = __builtin_amdgcn_mfma_f32_32x32x16_bf16(a0, b0, acc[0], 0, 0, 0);
            acc[1] = __builtin_amdgcn_mfma_f32_32x32x16_bf16(a0, b1, acc[1], 0, 0, 0);
        }
        // post-barrier weight DMA(kt+1) -> wtile[nxt]
        if (kt < 35) {
            const char* gb = (const char*)(wKg + (size_t)(kt + 1) * 16384);
            char* lb = (char*)&wtile[nxt][0][0][0];
            #pragma unroll
            for (int i = 0; i < 4; i++) {
                int off = i * 8192 + wid * 1024;
                __builtin_amdgcn_global_load_lds(
                    (const __attribute__((address_space(1))) void*)(gb + off + lane * 16),
                    (__attribute__((address_space(3))) void*)(lb + off), 16, 0, 0);
            }
        }
    }

    // epilogue: bias + store NCHW f32
    #pragma unroll
    for (int fp = 0; fp < 2; fp++) {
        #pragma unroll
        for (int r = 0; r < 16; r++) {
            int o = o0 + (r & 3) + ((r >> 2) << 3) + (lhi << 2);
            size_t rowoff = ((size_t)(b * 256 + o) << 12) + pib0;
            out[rowoff + fp * 32 + lrow] = acc[fp][r] + bias[o];
        }
    }
}

extern "C" void kernel_launch(void* const* d_in, const int* in_sizes, int n_in,
                              void* d_out, int out_size, void* d_ws, size_t ws_size,
                              hipStream_t stream)
{
    const float* x        = (const float*)d_in[0];
    const float* S        = (const float*)d_in[1];
    const float* sp_w1    = (const float*)d_in[2];
    const float* sp_b1    = (const float*)d_in[3];
    const float* sp_s1    = (const float*)d_in[4];
    const float* sp_o1    = (const float*)d_in[5];
    const float* sp_w2    = (const float*)d_in[6];
    const float* sp_b2    = (const float*)d_in[7];
    const float* sp_s2    = (const float*)d_in[8];
    const float* sp_o2    = (const float*)d_in[9];
    const float* sp_w3    = (const float*)d_in[10];
    const float* sp_b3    = (const float*)d_in[11];
    const float* sp_s3    = (const float*)d_in[12];
    const float* sp_o3    = (const float*)d_in[13];
    const float* off_w    = (const float*)d_in[14];
    const float* off_b    = (const float*)d_in[15];
    const float* dc_off_w = (const float*)d_in[16];
    const float* dc_off_b = (const float*)d_in[17];
    const float* dc_w     = (const float*)d_in[18];
    const float* m_w      = (const float*)d_in[19];
    const float* m_b      = (const float*)d_in[20];
    const float* weight   = (const float*)d_in[21];
    const float* bias     = (const float*)d_in[22];
    float* out = (float*)d_out;
    float* ws  = (float*)d_ws;

    u16*   xTb   = (u16*)(ws + OXT);
    float* Si    = ws + OSI;
    u16*   h1    = (u16*)(ws + OA);
    u16*   h2    = (u16*)(ws + OB);
    u16*   h3    = (u16*)(ws + OC);
    float* offsb = ws + OOFFS;
    float* maskb = ws + OMSK;

    prologue_k<<<5320, 256, 0, stream>>>(weight, sp_w1, sp_s1, sp_w2, sp_s2,
                                         sp_w3, sp_s3, off_w, dc_off_w, dc_w,
                                         sp_b1, sp_o1, sp_b2, sp_o2, sp_b3, sp_o3,
                                         off_b, dc_off_b, x, S, ws);
    conv_in_k<<<512, 256, 0, stream>>>(Si, ws + OWSP1, ws + OBSP1, h1);
    conv_mfma_k<0, true><<<512, 256, 0, stream>>>(h1, (const u16*)(ws + OWSP2),
                                                  ws + OBSP2, h2, nullptr);
    conv_mfma_k<0, true><<<512, 256, 0, stream>>>(h2, (const u16*)(ws + OWSP3),
                                                  ws + OBSP3, h3, nullptr);
    conv_mfma_k<1, false><<<512, 256, 0, stream>>>(h3, (const u16*)(ws + OWOFF),
                                                   ws + OBOFF, nullptr, offsb);
    dconv_small_mfma<<<256, 512, 0, stream>>>(h3, offsb, (const u16*)(ws + OWDC),
                                              m_w, m_b, maskb);
    dconv_big_mfma<<<512, 512, 0, stream>>>(xTb, offsb, maskb,
                                            (const u16*)(ws + OWT), bias, out);
}

// Round 15
// 122.526 us; speedup vs baseline: 1.1227x; 1.1227x over previous
//
#include <hip/hip_runtime.h>
#include <hip/hip_bf16.h>

typedef unsigned short u16;
typedef unsigned int u32;
typedef __attribute__((ext_vector_type(8))) short short8;
typedef __attribute__((ext_vector_type(4))) unsigned short ush4;
typedef __attribute__((ext_vector_type(16))) float f32x16;

// ---------------------------------------------------------------------------
// ws layout (float units): see prior rounds.
// ---------------------------------------------------------------------------
#define OXT   0
#define OSI   (OXT + 8388608)
#define OA    (OSI + 98304)
#define OB    (OA + 2097152)
#define OC    (OB + 2097152)
#define OOFFS (OC + 2097152)
#define OMSK  (OOFFS + 1179648)
#define OWT   (OMSK + 294912)
#define OWSP1 (OWT + 589824)
#define OBSP1 (OWSP1 + 1728)
#define OWSP2 (OBSP1 + 64)
#define OBSP2 (OWSP2 + 36864)
#define OWSP3 (OBSP2 + 64)
#define OBSP3 (OWSP3 + 36864)
#define OWOFF (OBSP3 + 64)
#define OBOFF (OWOFF + 36864)
#define OWDC  (OBOFF + 64)

__device__ __forceinline__ u16 f2bf(float f) {
    __hip_bfloat16 hb = __float2bfloat16(f);
    return __builtin_bit_cast(u16, hb);
}
__device__ __forceinline__ float bf2f(u16 v) {
    return __builtin_bit_cast(float, (u32)v << 16);
}
// XOR slot swizzle: data (kg, px) lives at row kg, slot = px with low3 ^ kg.
__device__ __forceinline__ int sswz(int kg, int px) {
    return (px & ~7) | ((px ^ kg) & 7);
}

// corner table for one (tap, pixel): 4 addresses (element offsets) + weights
__device__ __forceinline__ void corner_tab_big(
    int tap, int pix0, int b, int gp,
    const float* __restrict__ offs, const float* __restrict__ maskb,
    int* car, float* cwr)
{
    int pix = pix0 + gp; int pib = pix & 4095;
    int y = pib >> 6, x = pib & 63;
    float offy = offs[(size_t)pix * 36 + tap * 2];
    float offx = offs[(size_t)pix * 36 + tap * 2 + 1];
    float m = maskb[(size_t)pix * 9 + tap];
    float py = (float)(y - 1 + tap / 3) + offy;
    float pxf = (float)(x - 1 + (tap % 3)) + offx;
    float fy = floorf(py), fx = floorf(pxf);
    int y0 = (int)fy, x0 = (int)fx;
    float dyf = py - fy, dxf = pxf - fx;
    #pragma unroll
    for (int j = 0; j < 4; j++) {
        float wj = ((j >> 1) ? dyf : 1.f - dyf) * ((j & 1) ? dxf : 1.f - dxf);
        int yy = y0 + (j >> 1), xx = x0 + (j & 1);
        bool valid = (yy >= 0 && yy < 64 && xx >= 0 && xx < 64);
        int yc = min(max(yy, 0), 63), xc = min(max(xx, 0), 63);
        car[j] = (b * 4096 + yc * 64 + xc) << 8;
        cwr[j] = valid ? wj * m : 0.f;
    }
}

__device__ __forceinline__ void corner_tab_small(
    int tap, int pix0, int b, int gp,
    const float* __restrict__ offs, int* car, float* cwr)
{
    int pix = pix0 + gp; int pib = pix & 4095;
    int y = pib >> 6, x = pib & 63;
    float offy = offs[(size_t)pix * 36 + 18 + tap * 2];
    float offx = offs[(size_t)pix * 36 + 18 + tap * 2 + 1];
    float py = (float)(y - 1 + tap / 3) + offy;
    float pxf = (float)(x - 1 + (tap % 3)) + offx;
    float fy = floorf(py), fx = floorf(pxf);
    int y0 = (int)fy, x0 = (int)fx;
    float dyf = py - fy, dxf = pxf - fx;
    #pragma unroll
    for (int j = 0; j < 4; j++) {
        float wj = ((j >> 1) ? dyf : 1.f - dyf) * ((j & 1) ? dxf : 1.f - dxf);
        int yy = y0 + (j >> 1), xx = x0 + (j & 1);
        bool valid = (yy >= 0 && yy < 64 && xx >= 0 && xx < 64);
        int yc = min(max(yy, 0), 63), xc = min(max(xx, 0), 63);
        car[j] = (b * 4096 + yc * 64 + xc) << 6;
        cwr[j] = valid ? wj : 0.f;
    }
}

// ---------------------------------------------------------------------------
// Fused prologue: prep (blocks 0..2887) | transpose_x (2888..4935) |
// resize (4936..5319).
// ---------------------------------------------------------------------------
__global__ __launch_bounds__(256) void prologue_k(
    const float* __restrict__ weight,
    const float* __restrict__ sp_w1, const float* __restrict__ sp_s1,
    const float* __restrict__ sp_w2, const float* __restrict__ sp_s2,
    const float* __restrict__ sp_w3, const float* __restrict__ sp_s3,
    const float* __restrict__ off_w, const float* __restrict__ dc_off_w,
    const float* __restrict__ dc_w,
    const float* __restrict__ sp_b1, const float* __restrict__ sp_o1,
    const float* __restrict__ sp_b2, const float* __restrict__ sp_o2,
    const float* __restrict__ sp_b3, const float* __restrict__ sp_o3,
    const float* __restrict__ off_b, const float* __restrict__ dc_off_b,
    const float* __restrict__ x, const float* __restrict__ S,
    float* __restrict__ ws)
{
    __shared__ float tile[64][65];
    int blk = blockIdx.x;
    int t = threadIdx.x;

    if (blk >= 4936) {                       // ---- resize ----
        int i = (blk - 4936) * 256 + t;
        if (i >= 8 * 64 * 64 * 3) return;
        int c = i % 3; int xq = (i / 3) & 63; int y = (i / 192) & 63; int b = i / 12288;
        const float sc = 127.0f / 63.0f;
        float sy = y * sc, sx = xq * sc;
        float fy = floorf(sy), fx = floorf(sx);
        int y0 = (int)fy, x0 = (int)fx;
        int y1 = min(y0 + 1, 127), x1 = min(x0 + 1, 127);
        float wy = sy - fy, wx = sx - fx;
        const float* Sb = S + (size_t)(b * 3 + c) * 16384;
        float v00 = Sb[y0 * 128 + x0], v01 = Sb[y0 * 128 + x1];
        float v10 = Sb[y1 * 128 + x0], v11 = Sb[y1 * 128 + x1];
        (ws + OSI)[i] = (v00 * (1.f - wy) + v10 * wy) * (1.f - wx)
                      + (v01 * (1.f - wy) + v11 * wy) * wx;
        return;
    }
    if (blk >= 2888) {                       // ---- transpose x -> xT bf16 ----
        int bb = blk - 2888;
        int chunk = bb & 3; int by = bb >> 2;
        int b = by >> 6; int y = by & 63;
        int c0 = chunk * 64;
        u16* xT = (u16*)(ws + OXT);
        for (int i = t; i < 4096; i += 256) {
            int ci = i >> 6, xi = i & 63;
            tile[ci][xi] = x[((b * 256 + c0 + ci) * 64 + y) * 64 + xi];
        }
        __syncthreads();
        for (int i = t; i < 4096; i += 256) {
            int xi = i >> 6, ci = i & 63;
            xT[((b * 64 + y) * 64 + xi) * 256 + c0 + ci] = f2bf(tile[ci][xi]);
        }
        return;
    }
    // ---- prep ----
    int i = blk * 256 + t;
    if (i < 589824) {   // wKg bf16 [kg][o][j], K=kg*8+j = k*256+c
        int j = i & 7; int o = (i >> 3) & 255; int kg = i >> 11;
        int K = kg * 8 + j; int k = K >> 8; int c = K & 255;
        ((u16*)(ws + OWT))[i] = f2bf(weight[o * 2304 + c * 9 + k]);
        return;
    }
    i -= 589824;
    if (i < 1728) {     // wsp1 f32 [9][3][64]
        int o = i & 63; int kc = i >> 6; int c = kc % 3; int k = kc / 3;
        ws[OWSP1 + i] = sp_w1[(o * 3 + c) * 9 + k] * sp_s1[o];
        return;
    }
    i -= 1728;
    if (i < 36864) {    // wm2 bf16 [t][kg][o][e]
        int e = i & 7; int o = (i >> 3) & 63; int kg = (i >> 9) & 7; int tp = i >> 12;
        ((u16*)(ws + OWSP2))[i] = f2bf(sp_w2[(o * 64 + kg * 8 + e) * 9 + tp] * sp_s2[o]);
        return;
    }
    i -= 36864;
    if (i < 36864) {
        int e = i & 7; int o = (i >> 3) & 63; int kg = (i >> 9) & 7; int tp = i >> 12;
        ((u16*)(ws + OWSP3))[i] = f2bf(sp_w3[(o * 64 + kg * 8 + e) * 9 + tp] * sp_s3[o]);
        return;
    }
    i -= 36864;
    if (i < 36864) {    // woff bf16
        int e = i & 7; int o = (i >> 3) & 63; int kg = (i >> 9) & 7; int tp = i >> 12;
        int c = kg * 8 + e;
        float v = 0.f;
        if (o < 18) v = off_w[(o * 64 + c) * 9 + tp];
        else if (o < 36) v = dc_off_w[((o - 18) * 64 + c) * 9 + tp];
        ((u16*)(ws + OWOFF))[i] = f2bf(v);
        return;
    }
    i -= 36864;
    if (i < 36864) {    // wdc bf16 [t][kg][o][e]
        int e = i & 7; int o = (i >> 3) & 63; int kg = (i >> 9) & 7; int tp = i >> 12;
        ((u16*)(ws + OWDC))[i] = f2bf(dc_w[(o * 64 + kg * 8 + e) * 9 + tp]);
        return;
    }
    i -= 36864;
    if (i < 64) { ws[OBSP1 + i] = sp_b1[i] * sp_s1[i] + sp_o1[i]; return; }
    i -= 64;
    if (i < 64) { ws[OBSP2 + i] = sp_b2[i] * sp_s2[i] + sp_o2[i]; return; }
    i -= 64;
    if (i < 64) { ws[OBSP3 + i] = sp_b3[i] * sp_s3[i] + sp_o3[i]; return; }
    i -= 64;
    if (i < 64) { ws[OBOFF + i] = (i < 18) ? off_b[i] : (i < 36 ? dc_off_b[i - 18] : 0.f); return; }
}

// conv1: 3->64, fp32 VALU, bf16 NHWC output. One block per (b,y) row.
__global__ __launch_bounds__(256) void conv_in_k(const float* __restrict__ in,
                                                 const float* __restrict__ wt,
                                                 const float* __restrict__ bias,
                                                 u16* __restrict__ out)
{
    __shared__ float rows[3][66][3];
    int by = blockIdx.x; int b = by >> 6; int y = by & 63;
    int t = threadIdx.x;
    for (int i = t; i < 3 * 66 * 3; i += 256) {
        int r = i / 198; int rem = i - r * 198;
        int xi = rem / 3; int c = rem - xi * 3;
        int yy = y - 1 + r, xx = xi - 1;
        float v = 0.f;
        if (yy >= 0 && yy < 64 && xx >= 0 && xx < 64)
            v = in[(((b * 64 + yy) * 64 + xx) * 3) + c];
        rows[r][xi][c] = v;
    }
    __syncthreads();
    int o4 = (t & 15) * 4; int xg = t >> 4;
    float acc[4][4];
    #pragma unroll
    for (int oi = 0; oi < 4; oi++) {
        float bv = bias[o4 + oi];
        #pragma unroll
        for (int xi = 0; xi < 4; xi++) acc[oi][xi] = bv;
    }
    for (int k = 0; k < 9; k++) {
        int dy = k / 3, dx = k - 3 * (k / 3);
        for (int c = 0; c < 3; c++) {
            float4 w = *reinterpret_cast<const float4*>(&wt[(k * 3 + c) * 64 + o4]);
            #pragma unroll
            for (int xi = 0; xi < 4; xi++) {
                float iv = rows[dy][xg * 4 + xi + dx][c];
                acc[0][xi] = fmaf(w.x, iv, acc[0][xi]);
                acc[1][xi] = fmaf(w.y, iv, acc[1][xi]);
                acc[2][xi] = fmaf(w.z, iv, acc[2][xi]);
                acc[3][xi] = fmaf(w.w, iv, acc[3][xi]);
            }
        }
    }
    #pragma unroll
    for (int xi = 0; xi < 4; xi++) {
        int x = xg * 4 + xi;
        ush4 v;
        v.x = f2bf(fmaxf(acc[0][xi], 0.f));
        v.y = f2bf(fmaxf(acc[1][xi], 0.f));
        v.z = f2bf(fmaxf(acc[2][xi], 0.f));
        v.w = f2bf(fmaxf(acc[3][xi], 0.f));
        *reinterpret_cast<ush4*>(&out[((size_t)(by * 64 + x)) * 64 + o4]) = v;
    }
}

// ---------------------------------------------------------------------------
// MFMA 3x3 conv 64->64, ALL-TAPS-PRELOADED: weights (72KB) staged once, then
// a barrier-free main loop of 36 MFMA. Block: 2 rows = 128 px, 8 waves
// = 2(o) x 4(px). Grid 256. LDS = 4-row halo 33.8KB + wtap 72KB = 105.5KB.
// ---------------------------------------------------------------------------
template <int MODE, bool RELU>
__global__ __launch_bounds__(512) void conv_mfma_k(const u16* __restrict__ in,
                                                   const u16* __restrict__ wm,
                                                   const float* __restrict__ bias,
                                                   u16* __restrict__ outH,
                                                   float* __restrict__ outF)
{
    __shared__ __attribute__((aligned(16))) char lds_h[4 * 66 * 128];   // 33792 B
    __shared__ __attribute__((aligned(16))) u16 wtap[9][8][64][8];      // 73728 B

    int t = threadIdx.x;
    int b = blockIdx.x >> 5; int y0 = (blockIdx.x & 31) * 2;
    int pix0 = b * 4096 + y0 * 64;
    int wid = t >> 6, lane = t & 63;
    int lrow = lane & 31, lhi = lane >> 5;
    int o0 = (wid & 1) << 5;
    int px0 = (wid >> 1) << 5;        // 4 px-groups of 32 over 128 px
    int px = px0 + lrow;
    int ry_l = px >> 6, xc = px & 63;

    // stage 4 input rows (y0-1 .. y0+2), 66 cols, swizzled
    for (int i = t; i < 4 * 66 * 8; i += 512) {
        int r = i / 528; int rem = i - r * 528;
        int xi = rem >> 3; int g = rem & 7;
        int yy = y0 - 1 + r, xx = xi - 1;
        short8 v = {0,0,0,0,0,0,0,0};
        if (yy >= 0 && yy < 64 && xx >= 0 && xx < 64)
            v = *reinterpret_cast<const short8*>(&in[(size_t)((b * 4096 + yy * 64 + xx)) * 64 + g * 8]);
        int byte = (r * 66 + xi) * 128 + ((g * 16) ^ ((xi & 7) << 4));
        *reinterpret_cast<short8*>(lds_h + byte) = v;
    }
    // stage ALL 9 taps of weights (73728 B = 9 rounds x 512thr x 16B)
    {
        const char* gb = (const char*)wm;
        char* lb = (char*)&wtap[0][0][0][0];
        #pragma unroll
        for (int i = 0; i < 9; i++) {
            int off = i * 8192 + wid * 1024;
            __builtin_amdgcn_global_load_lds(
                (const __attribute__((address_space(1))) void*)(gb + off + lane * 16),
                (__attribute__((address_space(3))) void*)(lb + off), 16, 0, 0);
        }
    }
    __syncthreads();   // drains vmcnt(0) lgkmcnt(0): halo + weights ready

    f32x16 acc;
    #pragma unroll
    for (int r = 0; r < 16; r++) acc[r] = 0.f;

    // barrier-free main loop: everything read-only in LDS
    #pragma unroll
    for (int tap = 0; tap < 9; tap++) {
        int dy = tap / 3, dx = tap - 3 * (tap / 3);
        int xi = xc + dx;
        int rowbyte = ((ry_l + dy) * 66 + xi) * 128;
        int swz = (xi & 7) << 4;
        #pragma unroll
        for (int ks = 0; ks < 4; ks++) {
            int kg = ks * 2 + lhi;
            short8 a0 = *reinterpret_cast<const short8*>(&wtap[tap][kg][o0 + lrow][0]);
            short8 b0 = *reinterpret_cast<const short8*>(lds_h + rowbyte + ((kg * 16) ^ swz));
            acc = __builtin_amdgcn_mfma_f32_32x32x16_bf16(a0, b0, acc, 0, 0, 0);
        }
    }
    __syncthreads();

    if (MODE == 0) {
        // transpose via LDS: [128 px][64 o] bf16, swizzled by (px&7)<<4
        #pragma unroll
        for (int q = 0; q < 4; q++) {
            int ob = o0 + q * 8 + 4 * lhi;
            #pragma unroll
            for (int h = 0; h < 2; h++) {
                float v0 = acc[q * 4 + h * 2] + bias[ob + h * 2];
                float v1 = acc[q * 4 + h * 2 + 1] + bias[ob + h * 2 + 1];
                if (RELU) { v0 = fmaxf(v0, 0.f); v1 = fmaxf(v1, 0.f); }
                u32 pk = (u32)f2bf(v0) | ((u32)f2bf(v1) << 16);
                int byte = px * 128 + (((ob + h * 2) * 2) ^ ((px & 7) << 4));
                *reinterpret_cast<u32*>(lds_h + byte) = pk;
            }
        }
        __syncthreads();
        #pragma unroll
        for (int i = 0; i < 2; i++) {
            int cid = i * 512 + t;       // 1024 chunks of 16B
            int p = cid >> 3, g = cid & 7;
            short8 v = *reinterpret_cast<const short8*>(lds_h + p * 128 + ((g * 16) ^ ((p & 7) << 4)));
            *reinterpret_cast<short8*>(&outH[(size_t)(pix0 + p) * 64 + g * 8]) = v;
        }
    } else {
        float* ltf = (float*)lds_h;      // [128][40] f32 = 20.5 KB
        #pragma unroll
        for (int r = 0; r < 16; r++) {
            int o = o0 + (r & 3) + ((r >> 2) << 3) + (lhi << 2);
            if (o < 36) ltf[px * 40 + o] = acc[r] + bias[o];
        }
        __syncthreads();
        for (int i = t; i < 1152; i += 512) {
            int p = i / 9, q = i - 9 * (i / 9);
            float4 v = *reinterpret_cast<const float4*>(&ltf[p * 40 + q * 4]);
            *reinterpret_cast<float4*>(&outF[(size_t)(pix0 + p) * 36 + q * 4]) = v;
        }
    }
}

// ---------------------------------------------------------------------------
// DCNv1 on h (bf16, 64->64) + fused mask head, ALL-TAPS-PRELOADED weights.
// 256 blocks x 512 thr; 128px x 64o. Reg-gather prefetch; one barrier/tap;
// NO in-loop weight DMA. LDS = wtile 72KB + stile dbuf 32KB = 104KB.
// ---------------------------------------------------------------------------
__global__ __launch_bounds__(512) void dconv_small_mfma(
    const u16* __restrict__ h, const float* __restrict__ offs,
    const u16* __restrict__ wdc, const float* __restrict__ m_w,
    const float* __restrict__ m_b, float* __restrict__ maskb)
{
    __shared__ __attribute__((aligned(16))) char smem[106496];
    u16 (*wtile)[8][64][8]  = (u16 (*)[8][64][8])smem;             // [9][8][64][8] 72KB
    u16 (*stile)[8][128][8] = (u16 (*)[8][128][8])(smem + 73728);  // [2][8][128][8] 32KB

    int t = threadIdx.x;
    int id = blockIdx.x;
    int blk = (id & 7) * 32 + (id >> 3);      // XCD swizzle
    int pix0 = blk * 128;
    int b = pix0 >> 12;
    int wid = t >> 6, lane = t & 63;
    int lrow = lane & 31, lhi = lane >> 5;
    int o0 = (wid & 1) << 5;
    int px0 = (wid >> 1) << 5;
    int gp = t >> 2, gsub = t & 3;            // pixel / 16-ch chunk

    int car[4]; float cwr[4];
    short8 g[8];

    // prologue: corners tap0 + gather tap0 into regs + ALL weight DMA
    corner_tab_small(0, pix0, b, gp, offs, car, cwr);
    {
        int c = gsub << 4;
        #pragma unroll
        for (int j = 0; j < 4; j++) {
            const u16* p = h + car[j] + c;
            g[j * 2]     = *reinterpret_cast<const short8*>(p);
            g[j * 2 + 1] = *reinterpret_cast<const short8*>(p + 8);
        }
    }
    {
        const char* gb = (const char*)wdc;
        char* lb = (char*)smem;
        #pragma unroll
        for (int i = 0; i < 9; i++) {
            int off = i * 8192 + wid * 1024;
            __builtin_amdgcn_global_load_lds(
                (const __attribute__((address_space(1))) void*)(gb + off + lane * 16),
                (__attribute__((address_space(3))) void*)(lb + off), 16, 0, 0);
        }
    }
    asm volatile("s_waitcnt vmcnt(0)" ::: "memory");   // weights (and gather) landed

    f32x16 acc;
    #pragma unroll
    for (int r = 0; r < 16; r++) acc[r] = 0.f;

    for (int tap = 0; tap < 9; ++tap) {
        int cur = tap & 1;

        // interp(tap): consume g regs -> stile[cur]
        float va[16];
        #pragma unroll
        for (int e = 0; e < 16; e++) va[e] = 0.f;
        #pragma unroll
        for (int j = 0; j < 4; j++) {
            float w = cwr[j];
            #pragma unroll
            for (int e = 0; e < 8; e++) {
                va[e]     = fmaf(w, bf2f((u16)g[j * 2][e]), va[e]);
                va[8 + e] = fmaf(w, bf2f((u16)g[j * 2 + 1][e]), va[8 + e]);
            }
        }
        short8 s0, s1;
        #pragma unroll
        for (int e = 0; e < 8; e++) { s0[e] = (short)f2bf(va[e]); s1[e] = (short)f2bf(va[8 + e]); }
        int kg0 = gsub * 2, kg1 = gsub * 2 + 1;
        *reinterpret_cast<short8*>(&stile[cur][kg0][sswz(kg0, gp)][0]) = s0;
        *reinterpret_cast<short8*>(&stile[cur][kg1][sswz(kg1, gp)][0]) = s1;

        // prefetch gather(tap+1) into regs (stays in flight across barrier)
        if (tap < 8) {
            corner_tab_small(tap + 1, pix0, b, gp, offs, car, cwr);
            int c = gsub << 4;
            #pragma unroll
            for (int j = 0; j < 4; j++) {
                const u16* p = h + car[j] + c;
                g[j * 2]     = *reinterpret_cast<const short8*>(p);
                g[j * 2 + 1] = *reinterpret_cast<const short8*>(p + 8);
            }
        }
        asm volatile("s_waitcnt lgkmcnt(0)" ::: "memory");
        __builtin_amdgcn_s_barrier();

        #pragma unroll
        for (int ks = 0; ks < 4; ks++) {
            int kg = ks * 2 + lhi;
            short8 a0 = *reinterpret_cast<const short8*>(&wtile[tap][kg][o0 + lrow][0]);
            short8 b0 = *reinterpret_cast<const short8*>(&stile[cur][kg][sswz(kg, px0 + lrow)][0]);
            acc = __builtin_amdgcn_mfma_f32_32x32x16_bf16(a0, b0, acc, 0, 0, 0);
        }
    }

    // epilogue: feat -> LDS [128][65] f32 (overlays wtile), then fused mask
    __syncthreads();
    float* featl = (float*)smem;
    int pxl = px0 + lrow;
    #pragma unroll
    for (int r = 0; r < 16; r++) {
        int o = o0 + (r & 3) + ((r >> 2) << 3) + (lhi << 2);
        featl[pxl * 65 + o] = acc[r];
    }
    __syncthreads();
    if (t < 256) {
        int p = t >> 1, hh = t & 1;
        int pix = pix0 + p;
        const float* fr = &featl[p * 65];
        int j0 = hh ? 4 : 0, j1 = hh ? 9 : 4;
        for (int j = j0; j < j1; j++) {
            float a = m_b[j];
            #pragma unroll 8
            for (int cc = 0; cc < 64; cc++) a = fmaf(fr[cc], m_w[j * 64 + cc], a);
            maskb[(size_t)pix * 9 + j] = 1.f / (1.f + expf(-a));
        }
    }
}

// ---------------------------------------------------------------------------
// Modulated DCNv2 (256->256), bf16 MFMA. (round-13 structure, best measured)
// 256 blocks x 512 thr; block = 128 px x 256 o; 8 waves = 4(o) x 2(px).
// LDS = wtile dbuf 64KB + stile dbuf 32KB = 96KB.
// Reg-gather prefetch + counted vmcnt(8); single barrier per kt.
// ---------------------------------------------------------------------------
__global__ __launch_bounds__(512) void dconv_big_mfma(
    const u16* __restrict__ xT, const float* __restrict__ offs,
    const float* __restrict__ maskb, const u16* __restrict__ wKg,
    const float* __restrict__ bias, float* __restrict__ out)
{
    __shared__ __attribute__((aligned(16))) u16 wtile[2][8][256][8];  // 64 KB
    __shared__ __attribute__((aligned(16))) u16 stile[2][8][128][8];  // 32 KB

    int t = threadIdx.x;
    int id = blockIdx.x;                       // 256
    int blk = (id & 7) * 32 + (id >> 3);       // XCD swizzle: image b -> XCD b
    int pix0 = blk * 128;
    int b = pix0 >> 12, pib0 = pix0 & 4095;
    int wid = t >> 6, lane = t & 63;
    int lrow = lane & 31, lhi = lane >> 5;
    int o0 = (wid & 3) << 6;                   // 4 o-groups of 64
    int px0 = (wid >> 2) << 6;                 // 2 px-groups of 64
    int gp = t >> 2, gsub = t & 3;             // gather: pixel / 16-ch chunk

    int car[4]; float cwr[4];
    short8 g[8];

    // prologue: corners tap0, gather loads kt0, weight stage kt0
    corner_tab_big(0, pix0, b, gp, offs, maskb, car, cwr);
    {
        int c = gsub << 4;
        #pragma unroll
        for (int j = 0; j < 4; j++) {
            const u16* p = xT + car[j] + c;
            g[j * 2]     = *reinterpret_cast<const short8*>(p);
            g[j * 2 + 1] = *reinterpret_cast<const short8*>(p + 8);
        }
    }
    {
        const char* gb = (const char*)wKg;
        char* lb = (char*)&wtile[0][0][0][0];
        #pragma unroll
        for (int i = 0; i < 4; i++) {
            int off = i * 8192 + wid * 1024;
            __builtin_amdgcn_global_load_lds(
                (const __attribute__((address_space(1))) void*)(gb + off + lane * 16),
                (__attribute__((address_space(3))) void*)(lb + off), 16, 0, 0);
        }
    }

    f32x16 acc[2][2];
    #pragma unroll
    for (int ao = 0; ao < 2; ao++)
        #pragma unroll
        for (int bp = 0; bp < 2; bp++)
            #pragma unroll
            for (int r = 0; r < 16; r++) acc[ao][bp][r] = 0.f;

    for (int kt = 0; kt < 36; ++kt) {
        int cur = kt & 1, nxt = cur ^ 1;

        // 1: consume gather regs -> interp -> stile[cur]
        float va[16];
        #pragma unroll
        for (int e = 0; e < 16; e++) va[e] = 0.f;
        #pragma unroll
        for (int j = 0; j < 4; j++) {
            float w = cwr[j];
            #pragma unroll
            for (int e = 0; e < 8; e++) {
                va[e]     = fmaf(w, bf2f((u16)g[j * 2][e]), va[e]);
                va[8 + e] = fmaf(w, bf2f((u16)g[j * 2 + 1][e]), va[8 + e]);
            }
        }
        short8 s0, s1;
        #pragma unroll
        for (int e = 0; e < 8; e++) { s0[e] = (short)f2bf(va[e]); s1[e] = (short)f2bf(va[8 + e]); }
        int kg0 = gsub * 2, kg1 = gsub * 2 + 1;
        *reinterpret_cast<short8*>(&stile[cur][kg0][sswz(kg0, gp)][0]) = s0;
        *reinterpret_cast<short8*>(&stile[cur][kg1][sswz(kg1, gp)][0]) = s1;

        // 2-3: next corners (tap boundary) + issue next gather loads to regs
        if (kt < 35) {
            if (((kt + 1) & 3) == 0)
                corner_tab_big((kt + 1) >> 2, pix0, b, gp, offs, maskb, car, cwr);
            int c = (((kt + 1) & 3) << 6) + (gsub << 4);
            #pragma unroll
            for (int j = 0; j < 4; j++) {
                const u16* p = xT + car[j] + c;
                g[j * 2]     = *reinterpret_cast<const short8*>(p);
                g[j * 2 + 1] = *reinterpret_cast<const short8*>(p + 8);
            }
            // keep the 8 fresh gather loads in flight; drain weight prefetch
            asm volatile("s_waitcnt vmcnt(8) lgkmcnt(0)" ::: "memory");
        } else {
            asm volatile("s_waitcnt vmcnt(0) lgkmcnt(0)" ::: "memory");
        }
        __builtin_amdgcn_s_barrier();

        // 4: MFMA phase (4 o x 2 px wave grid; a-frags reused over 2 b-frags)
        #pragma unroll
        for (int ks = 0; ks < 4; ks++) {
            int kg = ks * 2 + lhi;
            short8 a0 = *reinterpret_cast<const short8*>(&wtile[cur][kg][o0 + lrow][0]);
            short8 a1 = *reinterpret_cast<const short8*>(&wtile[cur][kg][o0 + 32 + lrow][0]);
            short8 b0 = *reinterpret_cast<const short8*>(&stile[cur][kg][sswz(kg, px0 + lrow)][0]);
            short8 b1 = *reinterpret_cast<const short8*>(&stile[cur][kg][sswz(kg, px0 + 32 + lrow)][0]);
            acc[0][0] = __builtin_amdgcn_mfma_f32_32x32x16_bf16(a0, b0, acc[0][0], 0, 0, 0);
            acc[0][1] = __builtin_amdgcn_mfma_f32_32x32x16_bf16(a0, b1, acc[0][1], 0, 0, 0);
            acc[1][0] = __builtin_amdgcn_mfma_f32_32x32x16_bf16(a1, b0, acc[1][0], 0, 0, 0);
            acc[1][1] = __builtin_amdgcn_mfma_f32_32x32x16_bf16(a1, b1, acc[1][1], 0, 0, 0);
        }
        // 5: post-barrier weight prefetch (into wtile[nxt])
        if (kt < 35) {
            const char* gb = (const char*)(wKg + (size_t)(kt + 1) * 16384);
            char* lb = (char*)&wtile[nxt][0][0][0];
            #pragma unroll
            for (int i = 0; i < 4; i++) {
                int off = i * 8192 + wid * 1024;
                __builtin_amdgcn_global_load_lds(
                    (const __attribute__((address_space(1))) void*)(gb + off + lane * 16),
                    (__attribute__((address_space(3))) void*)(lb + off), 16, 0, 0);
            }
        }
    }

    // epilogue: bias + store NCHW f32
    #pragma unroll
    for (int ao = 0; ao < 2; ao++) {
        #pragma unroll
        for (int r = 0; r < 16; r++) {
            int o = o0 + ao * 32 + (r & 3) + ((r >> 2) << 3) + (lhi << 2);
            float bv = bias[o];
            size_t rowoff = ((size_t)(b * 256 + o) << 12) + pib0 + px0;
            out[rowoff + lrow] = acc[ao][0][r] + bv;
            out[rowoff + 32 + lrow] = acc[ao][1][r] + bv;
        }
    }
}

extern "C" void kernel_launch(void* const* d_in, const int* in_sizes, int n_in,
                              void* d_out, int out_size, void* d_ws, size_t ws_size,
                              hipStream_t stream)
{
    const float* x        = (const float*)d_in[0];
    const float* S        = (const float*)d_in[1];
    const float* sp_w1    = (const float*)d_in[2];
    const float* sp_b1    = (const float*)d_in[3];
    const float* sp_s1    = (const float*)d_in[4];
    const float* sp_o1    = (const float*)d_in[5];
    const float* sp_w2    = (const float*)d_in[6];
    const float* sp_b2    = (const float*)d_in[7];
    const float* sp_s2    = (const float*)d_in[8];
    const float* sp_o2    = (const float*)d_in[9];
    const float* sp_w3    = (const float*)d_in[10];
    const float* sp_b3    = (const float*)d_in[11];
    const float* sp_s3    = (const float*)d_in[12];
    const float* sp_o3    = (const float*)d_in[13];
    const float* off_w    = (const float*)d_in[14];
    const float* off_b    = (const float*)d_in[15];
    const float* dc_off_w = (const float*)d_in[16];
    const float* dc_off_b = (const float*)d_in[17];
    const float* dc_w     = (const float*)d_in[18];
    const float* m_w      = (const float*)d_in[19];
    const float* m_b      = (const float*)d_in[20];
    const float* weight   = (const float*)d_in[21];
    const float* bias     = (const float*)d_in[22];
    float* out = (float*)d_out;
    float* ws  = (float*)d_ws;

    u16*   xTb   = (u16*)(ws + OXT);
    float* Si    = ws + OSI;
    u16*   h1    = (u16*)(ws + OA);
    u16*   h2    = (u16*)(ws + OB);
    u16*   h3    = (u16*)(ws + OC);
    float* offsb = ws + OOFFS;
    float* maskb = ws + OMSK;

    prologue_k<<<5320, 256, 0, stream>>>(weight, sp_w1, sp_s1, sp_w2, sp_s2,
                                         sp_w3, sp_s3, off_w, dc_off_w, dc_w,
                                         sp_b1, sp_o1, sp_b2, sp_o2, sp_b3, sp_o3,
                                         off_b, dc_off_b, x, S, ws);
    conv_in_k<<<512, 256, 0, stream>>>(Si, ws + OWSP1, ws + OBSP1, h1);
    conv_mfma_k<0, true><<<256, 512, 0, stream>>>(h1, (const u16*)(ws + OWSP2),
                                                  ws + OBSP2, h2, nullptr);
    conv_mfma_k<0, true><<<256, 512, 0, stream>>>(h2, (const u16*)(ws + OWSP3),
                                                  ws + OBSP3, h3, nullptr);
    conv_mfma_k<1, false><<<256, 512, 0, stream>>>(h3, (const u16*)(ws + OWOFF),
                                                   ws + OBOFF, nullptr, offsb);
    dconv_small_mfma<<<256, 512, 0, stream>>>(h3, offsb, (const u16*)(ws + OWDC),
                                              m_w, m_b, maskb);
    dconv_big_mfma<<<256, 512, 0, stream>>>(xTb, offsb, maskb,
                                            (const u16*)(ws + OWT), bias, out);
}